// Round 8
// baseline (894.925 us; speedup 1.0000x reference)
//
#include <hip/hip_runtime.h>

#define BB   16384
#define NAg  5
#define DD   128
#define HH   128
#define G4   512   // 4*H
#define KC   256   // LS1 + H
#define AA   64
#define CATW 768   // 6*H

typedef __attribute__((ext_vector_type(8))) short bf16x8;
typedef __attribute__((ext_vector_type(4))) float f32x4;

#define DEV static __device__ __forceinline__

DEV unsigned short bf16r(float x){
  unsigned u = __float_as_uint(x);
  unsigned r = (u + 0x7fffu + ((u >> 16) & 1u)) >> 16;
  return (unsigned short)r;
}
DEV float sigf(float x){ return 1.0f / (1.0f + __expf(-x)); }
DEV float tanhf_(float x){ return 2.0f / (1.0f + __expf(-2.0f * x)) - 1.0f; }

DEV bf16x8 ld8(const unsigned short* p){ return *(const bf16x8*)p; }

DEV bf16x8 cvt8(const float* __restrict__ p){
  const float4* q = (const float4*)p;
  float4 v0 = q[0], v1 = q[1];
  bf16x8 r;
  r[0]=(short)bf16r(v0.x); r[1]=(short)bf16r(v0.y); r[2]=(short)bf16r(v0.z); r[3]=(short)bf16r(v0.w);
  r[4]=(short)bf16r(v1.x); r[5]=(short)bf16r(v1.y); r[6]=(short)bf16r(v1.z); r[7]=(short)bf16r(v1.w);
  return r;
}

// DMA one 32KB W tile (global, pre-swizzle-packed) -> LDS, per-wave linear.
DEV void dma_tile(const unsigned short* __restrict__ g, unsigned short* l,
                  int w, int lane){
  #pragma unroll
  for (int rnd = 0; rnd < 4; ++rnd) {
    __builtin_amdgcn_global_load_lds(
      (const unsigned int*)(g + rnd*4096 + w*512 + lane*8),
      (unsigned int*)(l + rnd*4096 + w*512), 16, 0, 0);
  }
}

// ---------------- prep: pack weights bf16; Wc -> swizzled kt-tiles ----------
__global__ void k_prep(const float* __restrict__ d1w, const float* __restrict__ d2w,
                       const float* __restrict__ mWih, const float* __restrict__ mWhh,
                       const float* __restrict__ mbih, const float* __restrict__ mbhh,
                       const float* __restrict__ cWih, const float* __restrict__ cWhh,
                       const float* __restrict__ cbih, const float* __restrict__ cbhh,
                       unsigned short* d1w_bf, unsigned short* d2w_bf,
                       unsigned short* Wm, unsigned short* Wc, float* bm, float* bc)
{
  const long long TOT = 16384 + 49152 + 655360 + 655360 + 2560 + 2560;
  for (long long i = (long long)blockIdx.x * 256 + threadIdx.x; i < TOT;
       i += (long long)gridDim.x * 256) {
    long long x = i;
    if (x < 16384) { d1w_bf[x] = bf16r(d1w[x]); continue; }
    x -= 16384;
    if (x < 49152) { d2w_bf[x] = bf16r(d2w[x]); continue; }
    x -= 49152;
    if (x < 655360) {
      int k = (int)(x & 255); long long gg = x >> 8; // n*512+g  (k_mem layout)
      Wm[x] = bf16r(k < 128 ? mWih[gg * 128 + k] : mWhh[gg * 128 + (k - 128)]);
      continue;
    }
    x -= 655360;
    if (x < 655360) {
      // Wc packed: [l0][kt][g][32] with 16B-slot XOR swizzle
      int e  = (int)(x & 31);
      int g  = (int)((x >> 5) & 511);
      int tl = (int)(x >> 14);            // l0*8 + kt
      int l0 = tl >> 3, kt = tl & 7;
      int sp = e >> 3, w16 = e & 7;
      int s  = sp ^ (g & 3) ^ ((g >> 2) & 3);
      int k  = kt * 32 + s * 8 + w16;
      Wc[x] = bf16r(k < 128 ? cWih[((size_t)l0 * 512 + g) * 128 + k]
                            : cWhh[((size_t)l0 * 512 + g) * 128 + (k - 128)]);
      continue;
    }
    x -= 655360;
    if (x < 2560) { bm[x] = mbih[x] + mbhh[x]; continue; }
    x -= 2560;
    bc[x] = cbih[x] + cbhh[x];
  }
}

// ---------------- obs = input @ d1_w^T + d1_b -> bf16 (n,b,128), staged ------
__global__ __launch_bounds__(256) void k_obs(const float* __restrict__ input,
                                             const unsigned short* __restrict__ d1w,
                                             const float* __restrict__ d1b,
                                             unsigned short* __restrict__ obs_bf)
{
  __shared__ __align__(16) unsigned short ob[64][128];

  const int m0 = blockIdx.x * 64;
  const int w = threadIdx.x >> 6, l = threadIdx.x & 63;
  const int c0l = l & 15, hi = l >> 4;

  const int arow_m = m0 + w * 16 + c0l;           // m = n*B + b
  const int n = arow_m >> 14, b = arow_m & 16383;
  const float* arow = input + ((size_t)b * NAg + n) * DD;

  f32x4 acc[8];
  #pragma unroll
  for (int nt = 0; nt < 8; nt++) acc[nt] = (f32x4){0, 0, 0, 0};

  #pragma unroll
  for (int kt = 0; kt < 4; ++kt) {
    const int k = kt * 32 + hi * 8;
    bf16x8 a = cvt8(arow + k);
    #pragma unroll
    for (int nt = 0; nt < 8; nt++) {
      bf16x8 bfr = ld8(d1w + (size_t)(nt * 16 + c0l) * DD + k);
      acc[nt] = __builtin_amdgcn_mfma_f32_16x16x32_bf16(a, bfr, acc[nt], 0, 0, 0);
    }
  }
  #pragma unroll
  for (int nt = 0; nt < 8; nt++) {
    const int col = nt * 16 + c0l;
    const float bias = d1b[col];
    #pragma unroll
    for (int j = 0; j < 4; j++) {
      const int lr = w * 16 + hi * 4 + j;
      ob[lr][col ^ ((lr & 7) << 3)] = bf16r(acc[nt][j] + bias);
    }
  }
  __syncthreads();
  #pragma unroll
  for (int cc = 0; cc < 4; ++cc) {
    const int idx = cc * 256 + threadIdx.x;
    const int r = idx >> 4;
    const int c8 = (idx & 15) << 3;
    bf16x8 v = *(const bf16x8*)&ob[r][c8 ^ ((r & 7) << 3)];
    *(bf16x8*)(obs_bf + (size_t)(m0 + r) * DD + c8) = v;
  }
}

// ---------------- mem LSTM (one step), BM=64; cat slice staged in LDS --------
__global__ __launch_bounds__(256, 2) void k_mem(const unsigned short* __restrict__ obs_bf,
                                                const float* __restrict__ h0,
                                                const float* __restrict__ c0,
                                                const unsigned short* __restrict__ Wm,
                                                const float* __restrict__ bm,
                                                float* __restrict__ out_h,
                                                float* __restrict__ out_c,
                                                unsigned short* __restrict__ cat)
{
  __shared__ __align__(16) unsigned short hm[64][128];

  const int n = blockIdx.x >> 8;
  const int b0 = (blockIdx.x & 255) << 6;
  const int w = threadIdx.x >> 6, l = threadIdx.x & 63;
  const int c0l = l & 15, hi = l >> 4;

  const unsigned short* Wn = Wm + (size_t)n * G4 * KC;
  f32x4 acc[4][8];
  #pragma unroll
  for (int mt = 0; mt < 4; mt++)
    #pragma unroll
    for (int nt = 0; nt < 8; nt++) acc[mt][nt] = (f32x4){0, 0, 0, 0};

  #pragma unroll
  for (int kt = 0; kt < 8; ++kt) {
    const int k = kt * 32 + hi * 8;
    bf16x8 bfr[8];
    #pragma unroll
    for (int nt = 0; nt < 8; nt++) {
      const int g = (nt >> 1) * 128 + w * 32 + (nt & 1) * 16 + c0l;
      bfr[nt] = ld8(Wn + (size_t)g * KC + k);
    }
    bf16x8 a[4];
    #pragma unroll
    for (int mt = 0; mt < 4; mt++) {
      const int br = b0 + mt * 16 + c0l;
      if (kt < 4) a[mt] = ld8(obs_bf + ((size_t)n * BB + br) * DD + k);
      else        a[mt] = cvt8(h0 + ((size_t)n * BB + br) * HH + (k - 128));
    }
    #pragma unroll
    for (int mt = 0; mt < 4; mt++)
      #pragma unroll
      for (int nt = 0; nt < 8; nt++)
        acc[mt][nt] = __builtin_amdgcn_mfma_f32_16x16x32_bf16(a[mt], bfr[nt], acc[mt][nt], 0, 0, 0);
  }

  #pragma unroll
  for (int uhi = 0; uhi < 2; ++uhi) {
    const int u = w * 32 + uhi * 16 + c0l;
    const float bI = bm[n * G4 + u];
    const float bF = bm[n * G4 + 128 + u];
    const float bG = bm[n * G4 + 256 + u];
    const float bO = bm[n * G4 + 384 + u];
    #pragma unroll
    for (int mt = 0; mt < 4; mt++) {
      #pragma unroll
      for (int j = 0; j < 4; j++) {
        const int r = mt * 16 + hi * 4 + j;
        const size_t rb = (size_t)n * BB + b0 + r;
        const float iv = acc[mt][0 + uhi][j] + bI;
        const float fv = acc[mt][2 + uhi][j] + bF;
        const float gv = acc[mt][4 + uhi][j] + bG;
        const float ov = acc[mt][6 + uhi][j] + bO;
        const float cold = c0[rb * HH + u];
        const float cn = sigf(fv) * cold + sigf(iv) * tanhf_(gv);
        const float hn = sigf(ov) * tanhf_(cn);
        out_h[rb * HH + u] = hn;
        out_c[rb * HH + u] = cn;
        hm[r][u ^ ((r & 7) << 3)] = bf16r(hn);
      }
    }
  }
  __syncthreads();
  #pragma unroll
  for (int cc = 0; cc < 4; ++cc) {
    const int idx = cc * 256 + threadIdx.x;
    const int r = idx >> 4;
    const int c8 = (idx & 15) << 3;
    bf16x8 v = *(const bf16x8*)&hm[r][c8 ^ ((r & 7) << 3)];
    *(bf16x8*)(cat + ((size_t)n * BB + b0 + r) * CATW + 640 + c8) = v;
  }
}

// ---------------- fused com scan, m97-style pipelined ------------------------
// BM=128, 512 threads. W streamed via global_load_lds double-buffer (counted
// vmcnt, 2-barrier recipe). h via LDS double buffer; t=0 reads zeroed buffer.
__global__ __launch_bounds__(512, 2) void k_comf(const unsigned short* __restrict__ obs_bf,
                                                 const unsigned short* __restrict__ Wcp,
                                                 const float* __restrict__ bc,
                                                 unsigned short* __restrict__ cat)
{
  __shared__ __align__(16) unsigned short smem[65536];  // 128 KB
  unsigned short* hl = smem;            // [2][128][128]
  unsigned short* Wl = smem + 32768;    // [2][512][32] swizzled tiles

  const int bid = blockIdx.x;
  const int swz = (bid & 7) * 80 + (bid >> 3);      // 640 = 8*80, bijective
  const int l0 = swz >> 7;
  const int b0 = (swz & 127) << 7;
  const int tid = threadIdx.x;
  const int w = tid >> 6, lane = tid & 63;
  const int c0l = lane & 15, hi = lane >> 4;
  const int u = w * 16 + c0l;                        // hidden unit of this lane

  const unsigned short* Wg = Wcp + (size_t)l0 * (8 * 512 * 32);

  const float bI = bc[l0 * G4 + u];
  const float bF = bc[l0 * G4 + 128 + u];
  const float bG = bc[l0 * G4 + 256 + u];
  const float bO = bc[l0 * G4 + 384 + u];

  // zero h(-1) buffer (hl[1], read by t=0)
  for (int i = tid; i < 16384; i += 512) hl[16384 + i] = 0;

  // per-q W fragment LDS offsets (swizzled)
  int woff[4];
  #pragma unroll
  for (int q = 0; q < 4; q++) {
    const int g = q * 128 + u;
    woff[q] = g * 32 + ((hi ^ (g & 3) ^ ((g >> 2) & 3)) << 3);
  }

  float creg[8][4];
  #pragma unroll
  for (int mt = 0; mt < 8; mt++)
    #pragma unroll
    for (int j = 0; j < 4; j++) creg[mt][j] = 0.0f;

  // prologue: stage tiles 0,1
  dma_tile(Wg, Wl, w, lane);
  dma_tile(Wg + 16384, Wl + 16384, w, lane);

  for (int t = 0; t < 5; ++t) {
    const int it = (t == 4) ? l0 : (t + (t >= l0 ? 1 : 0));
    const unsigned short* obsb = obs_bf + ((size_t)it * BB + b0) * DD;
    const int rbuf = (t - 1) & 1, wbuf = t & 1;

    f32x4 acc[8][4];
    #pragma unroll
    for (int mt = 0; mt < 8; mt++)
      #pragma unroll
      for (int q = 0; q < 4; q++) acc[mt][q] = (f32x4){0, 0, 0, 0};

    for (int kt = 0; kt < 8; ++kt) {
      const int G = t * 8 + kt;
      if (G == 39) { asm volatile("s_waitcnt vmcnt(0)" ::: "memory"); }
      else         { asm volatile("s_waitcnt vmcnt(4)" ::: "memory"); }
      __syncthreads();

      const unsigned short* Wb = Wl + (G & 1) * 16384;
      bf16x8 bfr[4];
      #pragma unroll
      for (int q = 0; q < 4; q++) bfr[q] = ld8(Wb + woff[q]);

      #pragma unroll
      for (int mt = 0; mt < 8; mt++) {
        bf16x8 a;
        if (kt < 4) {
          a = ld8(obsb + (size_t)(mt * 16 + c0l) * DD + kt * 32 + hi * 8);
        } else {
          const int r = mt * 16 + c0l;
          const int col = ((kt - 4) * 32 + hi * 8) ^ ((r & 7) << 3);
          a = ld8(hl + rbuf * 16384 + r * 128 + col);
        }
        #pragma unroll
        for (int q = 0; q < 4; q++)
          acc[mt][q] = __builtin_amdgcn_mfma_f32_16x16x32_bf16(a, bfr[q], acc[mt][q], 0, 0, 0);
      }
      __syncthreads();

      const int Gn = G + 2;
      if (Gn < 40)
        dma_tile(Wg + (size_t)(Gn & 7) * 16384, Wl + (Gn & 1) * 16384, w, lane);
    }

    // epilogue: LSTM nonlinearity -> hl[wbuf]
    #pragma unroll
    for (int mt = 0; mt < 8; mt++) {
      #pragma unroll
      for (int j = 0; j < 4; j++) {
        const int r = mt * 16 + hi * 4 + j;
        const float iv = acc[mt][0][j] + bI;
        const float fv = acc[mt][1][j] + bF;
        const float gv = acc[mt][2][j] + bG;
        const float ov = acc[mt][3][j] + bO;
        const float cn = sigf(fv) * creg[mt][j] + sigf(iv) * tanhf_(gv);
        const float hn = sigf(ov) * tanhf_(cn);
        creg[mt][j] = cn;
        hl[wbuf * 16384 + r * 128 + (u ^ ((r & 7) << 3))] = bf16r(hn);
      }
    }
    __syncthreads();

    // coalesced wide copy hl[wbuf] -> cat
    unsigned short* catb = cat + ((size_t)it * BB + b0) * CATW + l0 * 128;
    #pragma unroll
    for (int cc = 0; cc < 4; ++cc) {
      const int idx = cc * 512 + tid;          // 0..2047
      const int r = idx >> 4;
      const int c8 = (idx & 15) << 3;
      bf16x8 v = ld8(hl + wbuf * 16384 + r * 128 + (c8 ^ ((r & 7) << 3)));
      *(bf16x8*)(catb + (size_t)r * CATW + c8) = v;
    }
  }
}

// ---------------- outs = cat @ d2_w^T + d2_b  -> d_out[0 .. 5*B*64) ----------
__global__ __launch_bounds__(256) void k_d2(const unsigned short* __restrict__ cat,
                                            const unsigned short* __restrict__ d2w,
                                            const float* __restrict__ d2b,
                                            float* __restrict__ out)
{
  const int m0 = blockIdx.x * 64;
  const int w = threadIdx.x >> 6, l = threadIdx.x & 63;
  const int c0l = l & 15, hi = l >> 4;

  const unsigned short* arow = cat + (size_t)(m0 + w * 16 + c0l) * CATW;
  f32x4 acc[4];
  #pragma unroll
  for (int nt = 0; nt < 4; nt++) acc[nt] = (f32x4){0, 0, 0, 0};

  #pragma unroll 4
  for (int kt = 0; kt < 24; ++kt) {
    const int k = kt * 32 + hi * 8;
    bf16x8 a = ld8(arow + k);
    #pragma unroll
    for (int nt = 0; nt < 4; nt++) {
      bf16x8 bfr = ld8(d2w + (size_t)(nt * 16 + c0l) * CATW + k);
      acc[nt] = __builtin_amdgcn_mfma_f32_16x16x32_bf16(a, bfr, acc[nt], 0, 0, 0);
    }
  }
  #pragma unroll
  for (int nt = 0; nt < 4; nt++) {
    const int col = nt * 16 + c0l;
    const float bias = d2b[col];
    #pragma unroll
    for (int j = 0; j < 4; j++) {
      const int r = m0 + w * 16 + hi * 4 + j;
      out[(size_t)r * AA + col] = acc[nt][j] + bias;
    }
  }
}

extern "C" void kernel_launch(void* const* d_in, const int* in_sizes, int n_in,
                              void* d_out, int out_size, void* d_ws, size_t ws_size,
                              hipStream_t stream)
{
  const float* input = (const float*)d_in[0];
  const float* h0    = (const float*)d_in[1];
  const float* c0    = (const float*)d_in[2];
  const float* d1w   = (const float*)d_in[3];
  const float* d1b   = (const float*)d_in[4];
  const float* d2w   = (const float*)d_in[5];
  const float* d2b   = (const float*)d_in[6];
  const float* mWih  = (const float*)d_in[7];
  const float* mWhh  = (const float*)d_in[8];
  const float* mbih  = (const float*)d_in[9];
  const float* mbhh  = (const float*)d_in[10];
  const float* cWih  = (const float*)d_in[11];
  const float* cWhh  = (const float*)d_in[12];
  const float* cbih  = (const float*)d_in[13];
  const float* cbhh  = (const float*)d_in[14];
  float* out = (float*)d_out;

  char* ws = (char*)d_ws;
  size_t off = 0;
  auto alloc = [&](size_t bytes) { void* p = ws + off; off += (bytes + 255) & ~255ull; return p; };
  unsigned short* d1w_bf = (unsigned short*)alloc(16384 * 2);
  unsigned short* d2w_bf = (unsigned short*)alloc(49152 * 2);
  unsigned short* Wm     = (unsigned short*)alloc(655360 * 2);
  unsigned short* Wcb    = (unsigned short*)alloc(655360 * 2);
  float* bm              = (float*)alloc(2560 * 4);
  float* bc              = (float*)alloc(2560 * 4);
  unsigned short* obs_bf = (unsigned short*)alloc((size_t)NAg * BB * DD * 2);
  unsigned short* cat    = (unsigned short*)alloc((size_t)NAg * BB * CATW * 2);

  float* out_h = out + (size_t)NAg * BB * AA;
  float* out_c = out_h + (size_t)NAg * BB * HH;

  k_prep<<<2048, 256, 0, stream>>>(d1w, d2w, mWih, mWhh, mbih, mbhh,
                                   cWih, cWhh, cbih, cbhh,
                                   d1w_bf, d2w_bf, Wm, Wcb, bm, bc);
  k_obs<<<(NAg * BB) / 64, 256, 0, stream>>>(input, d1w_bf, d1b, obs_bf);
  k_mem<<<(NAg * BB) / 64, 256, 0, stream>>>(obs_bf, h0, c0, Wm, bm, out_h, out_c, cat);
  k_comf<<<(NAg * BB) / 128, 512, 0, stream>>>(obs_bf, Wcb, bc, cat);
  k_d2<<<(NAg * BB) / 64, 256, 0, stream>>>(cat, d2w_bf, d2b, out);
}

// Round 9
// 446.638 us; speedup vs baseline: 2.0037x; 2.0037x over previous
//
#include <hip/hip_runtime.h>

#define BB   16384
#define NAg  5
#define DD   128
#define HH   128
#define G4   512   // 4*H
#define KC   256   // LS1 + H
#define AA   64
#define CATW 768   // 6*H

typedef __attribute__((ext_vector_type(8))) short bf16x8;
typedef __attribute__((ext_vector_type(4))) float f32x4;

#define DEV static __device__ __forceinline__

DEV unsigned short bf16r(float x){
  unsigned u = __float_as_uint(x);
  unsigned r = (u + 0x7fffu + ((u >> 16) & 1u)) >> 16;
  return (unsigned short)r;
}
DEV float sigf(float x){ return 1.0f / (1.0f + __expf(-x)); }
DEV float tanhf_(float x){ return 2.0f / (1.0f + __expf(-2.0f * x)) - 1.0f; }

DEV bf16x8 ld8(const unsigned short* p){ return *(const bf16x8*)p; }

DEV bf16x8 cvt8(const float* __restrict__ p){
  const float4* q = (const float4*)p;
  float4 v0 = q[0], v1 = q[1];
  bf16x8 r;
  r[0]=(short)bf16r(v0.x); r[1]=(short)bf16r(v0.y); r[2]=(short)bf16r(v0.z); r[3]=(short)bf16r(v0.w);
  r[4]=(short)bf16r(v1.x); r[5]=(short)bf16r(v1.y); r[6]=(short)bf16r(v1.z); r[7]=(short)bf16r(v1.w);
  return r;
}

// ---------------- prep: pack weights bf16; Wc -> per-wave reg-frag layout ----
// Wc packed as [l0][w][q][kt][lane][8]: lane(c0l=lane&15, hi=lane>>4) holds
// W[g = q*128 + w*16 + c0l][k = kt*32 + hi*8 + e] -> each wave frag load is a
// contiguous 1KB line.
__global__ void k_prep(const float* __restrict__ d1w, const float* __restrict__ d2w,
                       const float* __restrict__ mWih, const float* __restrict__ mWhh,
                       const float* __restrict__ mbih, const float* __restrict__ mbhh,
                       const float* __restrict__ cWih, const float* __restrict__ cWhh,
                       const float* __restrict__ cbih, const float* __restrict__ cbhh,
                       unsigned short* d1w_bf, unsigned short* d2w_bf,
                       unsigned short* Wm, unsigned short* Wc, float* bm, float* bc)
{
  const long long TOT = 16384 + 49152 + 655360 + 655360 + 2560 + 2560;
  for (long long i = (long long)blockIdx.x * 256 + threadIdx.x; i < TOT;
       i += (long long)gridDim.x * 256) {
    long long x = i;
    if (x < 16384) { d1w_bf[x] = bf16r(d1w[x]); continue; }
    x -= 16384;
    if (x < 49152) { d2w_bf[x] = bf16r(d2w[x]); continue; }
    x -= 49152;
    if (x < 655360) {
      int k = (int)(x & 255); long long gg = x >> 8; // n*512+g  (k_mem layout)
      Wm[x] = bf16r(k < 128 ? mWih[gg * 128 + k] : mWhh[gg * 128 + (k - 128)]);
      continue;
    }
    x -= 655360;
    if (x < 655360) {
      int e    = (int)(x & 7);
      int lane = (int)((x >> 3) & 63);
      int kt   = (int)((x >> 9) & 7);
      int q    = (int)((x >> 12) & 3);
      int w    = (int)((x >> 14) & 7);
      int l0   = (int)(x >> 17);
      int g = q * 128 + w * 16 + (lane & 15);
      int k = kt * 32 + (lane >> 4) * 8 + e;
      Wc[x] = bf16r(k < 128 ? cWih[((size_t)l0 * 512 + g) * 128 + k]
                            : cWhh[((size_t)l0 * 512 + g) * 128 + (k - 128)]);
      continue;
    }
    x -= 655360;
    if (x < 2560) { bm[x] = mbih[x] + mbhh[x]; continue; }
    x -= 2560;
    bc[x] = cbih[x] + cbhh[x];
  }
}

// ---------------- obs = input @ d1_w^T + d1_b -> bf16 (n,b,128), staged ------
__global__ __launch_bounds__(256) void k_obs(const float* __restrict__ input,
                                             const unsigned short* __restrict__ d1w,
                                             const float* __restrict__ d1b,
                                             unsigned short* __restrict__ obs_bf)
{
  __shared__ __align__(16) unsigned short ob[64][128];

  const int m0 = blockIdx.x * 64;
  const int w = threadIdx.x >> 6, l = threadIdx.x & 63;
  const int c0l = l & 15, hi = l >> 4;

  const int arow_m = m0 + w * 16 + c0l;           // m = n*B + b
  const int n = arow_m >> 14, b = arow_m & 16383;
  const float* arow = input + ((size_t)b * NAg + n) * DD;

  f32x4 acc[8];
  #pragma unroll
  for (int nt = 0; nt < 8; nt++) acc[nt] = (f32x4){0, 0, 0, 0};

  #pragma unroll
  for (int kt = 0; kt < 4; ++kt) {
    const int k = kt * 32 + hi * 8;
    bf16x8 a = cvt8(arow + k);
    #pragma unroll
    for (int nt = 0; nt < 8; nt++) {
      bf16x8 bfr = ld8(d1w + (size_t)(nt * 16 + c0l) * DD + k);
      acc[nt] = __builtin_amdgcn_mfma_f32_16x16x32_bf16(a, bfr, acc[nt], 0, 0, 0);
    }
  }
  #pragma unroll
  for (int nt = 0; nt < 8; nt++) {
    const int col = nt * 16 + c0l;
    const float bias = d1b[col];
    #pragma unroll
    for (int j = 0; j < 4; j++) {
      const int lr = w * 16 + hi * 4 + j;
      ob[lr][col ^ ((lr & 7) << 3)] = bf16r(acc[nt][j] + bias);
    }
  }
  __syncthreads();
  #pragma unroll
  for (int cc = 0; cc < 4; ++cc) {
    const int idx = cc * 256 + threadIdx.x;
    const int r = idx >> 4;
    const int c8 = (idx & 15) << 3;
    bf16x8 v = *(const bf16x8*)&ob[r][c8 ^ ((r & 7) << 3)];
    *(bf16x8*)(obs_bf + (size_t)(m0 + r) * DD + c8) = v;
  }
}

// ---------------- mem LSTM (one step), BM=64; cat slice staged in LDS --------
__global__ __launch_bounds__(256, 2) void k_mem(const unsigned short* __restrict__ obs_bf,
                                                const float* __restrict__ h0,
                                                const float* __restrict__ c0,
                                                const unsigned short* __restrict__ Wm,
                                                const float* __restrict__ bm,
                                                float* __restrict__ out_h,
                                                float* __restrict__ out_c,
                                                unsigned short* __restrict__ cat)
{
  __shared__ __align__(16) unsigned short hm[64][128];

  const int n = blockIdx.x >> 8;
  const int b0 = (blockIdx.x & 255) << 6;
  const int w = threadIdx.x >> 6, l = threadIdx.x & 63;
  const int c0l = l & 15, hi = l >> 4;

  const unsigned short* Wn = Wm + (size_t)n * G4 * KC;
  f32x4 acc[4][8];
  #pragma unroll
  for (int mt = 0; mt < 4; mt++)
    #pragma unroll
    for (int nt = 0; nt < 8; nt++) acc[mt][nt] = (f32x4){0, 0, 0, 0};

  #pragma unroll
  for (int kt = 0; kt < 8; ++kt) {
    const int k = kt * 32 + hi * 8;
    bf16x8 bfr[8];
    #pragma unroll
    for (int nt = 0; nt < 8; nt++) {
      const int g = (nt >> 1) * 128 + w * 32 + (nt & 1) * 16 + c0l;
      bfr[nt] = ld8(Wn + (size_t)g * KC + k);
    }
    bf16x8 a[4];
    #pragma unroll
    for (int mt = 0; mt < 4; mt++) {
      const int br = b0 + mt * 16 + c0l;
      if (kt < 4) a[mt] = ld8(obs_bf + ((size_t)n * BB + br) * DD + k);
      else        a[mt] = cvt8(h0 + ((size_t)n * BB + br) * HH + (k - 128));
    }
    #pragma unroll
    for (int mt = 0; mt < 4; mt++)
      #pragma unroll
      for (int nt = 0; nt < 8; nt++)
        acc[mt][nt] = __builtin_amdgcn_mfma_f32_16x16x32_bf16(a[mt], bfr[nt], acc[mt][nt], 0, 0, 0);
  }

  #pragma unroll
  for (int uhi = 0; uhi < 2; ++uhi) {
    const int u = w * 32 + uhi * 16 + c0l;
    const float bI = bm[n * G4 + u];
    const float bF = bm[n * G4 + 128 + u];
    const float bG = bm[n * G4 + 256 + u];
    const float bO = bm[n * G4 + 384 + u];
    #pragma unroll
    for (int mt = 0; mt < 4; mt++) {
      #pragma unroll
      for (int j = 0; j < 4; j++) {
        const int r = mt * 16 + hi * 4 + j;
        const size_t rb = (size_t)n * BB + b0 + r;
        const float iv = acc[mt][0 + uhi][j] + bI;
        const float fv = acc[mt][2 + uhi][j] + bF;
        const float gv = acc[mt][4 + uhi][j] + bG;
        const float ov = acc[mt][6 + uhi][j] + bO;
        const float cold = c0[rb * HH + u];
        const float cn = sigf(fv) * cold + sigf(iv) * tanhf_(gv);
        const float hn = sigf(ov) * tanhf_(cn);
        out_h[rb * HH + u] = hn;
        out_c[rb * HH + u] = cn;
        hm[r][u ^ ((r & 7) << 3)] = bf16r(hn);
      }
    }
  }
  __syncthreads();
  #pragma unroll
  for (int cc = 0; cc < 4; ++cc) {
    const int idx = cc * 256 + threadIdx.x;
    const int r = idx >> 4;
    const int c8 = (idx & 15) << 3;
    bf16x8 v = *(const bf16x8*)&hm[r][c8 ^ ((r & 7) << 3)];
    *(bf16x8*)(cat + ((size_t)n * BB + b0 + r) * CATW + 640 + c8) = v;
  }
}

// ---------------- fused com scan: W entirely in registers --------------------
// 512 thr / 8 waves; wave w owns hidden units [w*16, w*16+16), all 4 gates,
// full K=256: 32 B-frags = 128 VGPRs, loaded once. BM=64 rows processed in two
// 32-row halves (32 live acc). h transits via 32KB swizzled LDS double buffer.
// One __syncthreads per step.
__global__ __launch_bounds__(512, 2) void k_comf(const unsigned short* __restrict__ obs_bf,
                                                 const unsigned short* __restrict__ Wpk,
                                                 const float* __restrict__ bc,
                                                 unsigned short* __restrict__ cat)
{
  __shared__ __align__(16) unsigned short hl[2][64][128];   // 32 KB

  const int bid = blockIdx.x;
  const int swz = (bid & 7) * 160 + (bid >> 3);   // 1280 = 8*160, bijective
  const int l0 = swz >> 8;
  const int b0 = (swz & 255) << 6;
  const int tid = threadIdx.x;
  const int w = tid >> 6, lane = tid & 63;
  const int c0l = lane & 15, hi = lane >> 4;
  const int u = w * 16 + c0l;

  // ---- load all W fragments into registers (one contiguous 1KB line/frag) --
  const unsigned short* Wg = Wpk + (size_t)l0 * 131072 + (size_t)w * 16384 + lane * 8;
  bf16x8 wfr[4][8];
  #pragma unroll
  for (int q = 0; q < 4; q++)
    #pragma unroll
    for (int kt = 0; kt < 8; kt++)
      wfr[q][kt] = ld8(Wg + (q * 8 + kt) * 512);

  const float bI = bc[l0 * G4 + u];
  const float bF = bc[l0 * G4 + 128 + u];
  const float bG = bc[l0 * G4 + 256 + u];
  const float bO = bc[l0 * G4 + 384 + u];

  // zero h(-1) buffer (hl[1], read by t=0)
  for (int i = tid; i < 8192; i += 512) ((unsigned short*)hl)[8192 + i] = 0;
  __syncthreads();

  float creg[2][2][4];
  #pragma unroll
  for (int hh = 0; hh < 2; hh++)
    #pragma unroll
    for (int m2 = 0; m2 < 2; m2++)
      #pragma unroll
      for (int j = 0; j < 4; j++) creg[hh][m2][j] = 0.0f;

  for (int t = 0; t < 5; ++t) {
    const int it = (t == 4) ? l0 : (t + (t >= l0 ? 1 : 0));
    const unsigned short* obsb = obs_bf + ((size_t)it * BB + b0) * DD;
    const int rbuf = (t + 1) & 1, wbuf = t & 1;

    #pragma unroll
    for (int hh = 0; hh < 2; hh++) {
      f32x4 acc[2][4];
      #pragma unroll
      for (int m2 = 0; m2 < 2; m2++)
        #pragma unroll
        for (int q = 0; q < 4; q++) acc[m2][q] = (f32x4){0, 0, 0, 0};

      #pragma unroll
      for (int kt = 0; kt < 8; ++kt) {
        bf16x8 a[2];
        #pragma unroll
        for (int m2 = 0; m2 < 2; m2++) {
          const int r = (hh * 2 + m2) * 16 + c0l;
          if (kt < 4) a[m2] = ld8(obsb + (size_t)r * DD + kt * 32 + hi * 8);
          else        a[m2] = ld8(&hl[rbuf][r][((kt - 4) * 32 + hi * 8) ^ ((r & 7) << 3)]);
        }
        #pragma unroll
        for (int m2 = 0; m2 < 2; m2++)
          #pragma unroll
          for (int q = 0; q < 4; q++)
            acc[m2][q] = __builtin_amdgcn_mfma_f32_16x16x32_bf16(a[m2], wfr[q][kt], acc[m2][q], 0, 0, 0);
      }

      // epilogue for this 32-row half
      #pragma unroll
      for (int m2 = 0; m2 < 2; m2++) {
        #pragma unroll
        for (int j = 0; j < 4; j++) {
          const int r = hh * 32 + m2 * 16 + hi * 4 + j;
          const float iv = acc[m2][0][j] + bI;
          const float fv = acc[m2][1][j] + bF;
          const float gv = acc[m2][2][j] + bG;
          const float ov = acc[m2][3][j] + bO;
          const float cn = sigf(fv) * creg[hh][m2][j] + sigf(iv) * tanhf_(gv);
          const float hn = sigf(ov) * tanhf_(cn);
          creg[hh][m2][j] = cn;
          hl[wbuf][r][u ^ ((r & 7) << 3)] = bf16r(hn);
        }
      }
    }
    __syncthreads();

    // coalesced wide copy hl[wbuf] -> cat (full 128B lines); no barrier needed
    // after: next step reads the same buffer (read-read), writes the other.
    unsigned short* catb = cat + ((size_t)it * BB + b0) * CATW + l0 * 128;
    #pragma unroll
    for (int cc = 0; cc < 2; ++cc) {
      const int idx = cc * 512 + tid;          // 0..1023
      const int r = idx >> 4;
      const int c8 = (idx & 15) << 3;
      bf16x8 v = *(const bf16x8*)&hl[wbuf][r][c8 ^ ((r & 7) << 3)];
      *(bf16x8*)(catb + (size_t)r * CATW + c8) = v;
    }
  }
}

// ---------------- outs = cat @ d2_w^T + d2_b  -> d_out[0 .. 5*B*64) ----------
__global__ __launch_bounds__(256) void k_d2(const unsigned short* __restrict__ cat,
                                            const unsigned short* __restrict__ d2w,
                                            const float* __restrict__ d2b,
                                            float* __restrict__ out)
{
  const int m0 = blockIdx.x * 64;
  const int w = threadIdx.x >> 6, l = threadIdx.x & 63;
  const int c0l = l & 15, hi = l >> 4;

  const unsigned short* arow = cat + (size_t)(m0 + w * 16 + c0l) * CATW;
  f32x4 acc[4];
  #pragma unroll
  for (int nt = 0; nt < 4; nt++) acc[nt] = (f32x4){0, 0, 0, 0};

  #pragma unroll 4
  for (int kt = 0; kt < 24; ++kt) {
    const int k = kt * 32 + hi * 8;
    bf16x8 a = ld8(arow + k);
    #pragma unroll
    for (int nt = 0; nt < 4; nt++) {
      bf16x8 bfr = ld8(d2w + (size_t)(nt * 16 + c0l) * CATW + k);
      acc[nt] = __builtin_amdgcn_mfma_f32_16x16x32_bf16(a, bfr, acc[nt], 0, 0, 0);
    }
  }
  #pragma unroll
  for (int nt = 0; nt < 4; nt++) {
    const int col = nt * 16 + c0l;
    const float bias = d2b[col];
    #pragma unroll
    for (int j = 0; j < 4; j++) {
      const int r = m0 + w * 16 + hi * 4 + j;
      out[(size_t)r * AA + col] = acc[nt][j] + bias;
    }
  }
}

extern "C" void kernel_launch(void* const* d_in, const int* in_sizes, int n_in,
                              void* d_out, int out_size, void* d_ws, size_t ws_size,
                              hipStream_t stream)
{
  const float* input = (const float*)d_in[0];
  const float* h0    = (const float*)d_in[1];
  const float* c0    = (const float*)d_in[2];
  const float* d1w   = (const float*)d_in[3];
  const float* d1b   = (const float*)d_in[4];
  const float* d2w   = (const float*)d_in[5];
  const float* d2b   = (const float*)d_in[6];
  const float* mWih  = (const float*)d_in[7];
  const float* mWhh  = (const float*)d_in[8];
  const float* mbih  = (const float*)d_in[9];
  const float* mbhh  = (const float*)d_in[10];
  const float* cWih  = (const float*)d_in[11];
  const float* cWhh  = (const float*)d_in[12];
  const float* cbih  = (const float*)d_in[13];
  const float* cbhh  = (const float*)d_in[14];
  float* out = (float*)d_out;

  char* ws = (char*)d_ws;
  size_t off = 0;
  auto alloc = [&](size_t bytes) { void* p = ws + off; off += (bytes + 255) & ~255ull; return p; };
  unsigned short* d1w_bf = (unsigned short*)alloc(16384 * 2);
  unsigned short* d2w_bf = (unsigned short*)alloc(49152 * 2);
  unsigned short* Wm     = (unsigned short*)alloc(655360 * 2);
  unsigned short* Wcb    = (unsigned short*)alloc(655360 * 2);
  float* bm              = (float*)alloc(2560 * 4);
  float* bc              = (float*)alloc(2560 * 4);
  unsigned short* obs_bf = (unsigned short*)alloc((size_t)NAg * BB * DD * 2);
  unsigned short* cat    = (unsigned short*)alloc((size_t)NAg * BB * CATW * 2);

  float* out_h = out + (size_t)NAg * BB * AA;
  float* out_c = out_h + (size_t)NAg * BB * HH;

  k_prep<<<2048, 256, 0, stream>>>(d1w, d2w, mWih, mWhh, mbih, mbhh,
                                   cWih, cWhh, cbih, cbhh,
                                   d1w_bf, d2w_bf, Wm, Wcb, bm, bc);
  k_obs<<<(NAg * BB) / 64, 256, 0, stream>>>(input, d1w_bf, d1b, obs_bf);
  k_mem<<<(NAg * BB) / 64, 256, 0, stream>>>(obs_bf, h0, c0, Wm, bm, out_h, out_c, cat);
  k_comf<<<(NAg * BB) / 64, 512, 0, stream>>>(obs_bf, Wcb, bc, cat);
  k_d2<<<(NAg * BB) / 64, 256, 0, stream>>>(cat, d2w_bf, d2b, out);
}

// Round 10
// 427.578 us; speedup vs baseline: 2.0930x; 1.0446x over previous
//
#include <hip/hip_runtime.h>

#define BB   16384
#define NAg  5
#define DD   128
#define HH   128
#define G4   512   // 4*H
#define KC   256   // LS1 + H
#define AA   64
#define CATW 768   // 6*H

typedef __attribute__((ext_vector_type(8))) short bf16x8;
typedef __attribute__((ext_vector_type(4))) float f32x4;

#define DEV static __device__ __forceinline__

DEV unsigned short bf16r(float x){
  unsigned u = __float_as_uint(x);
  unsigned r = (u + 0x7fffu + ((u >> 16) & 1u)) >> 16;
  return (unsigned short)r;
}
// fast sigmoid/tanh: v_rcp_f32 (1 ULP) instead of IEEE division (~9 instrs)
DEV float sigf(float x){ return __builtin_amdgcn_rcpf(1.0f + __expf(-x)); }
DEV float tanhf_(float x){ return __builtin_fmaf(2.0f, __builtin_amdgcn_rcpf(1.0f + __expf(-2.0f * x)), -1.0f); }

DEV bf16x8 ld8(const unsigned short* p){ return *(const bf16x8*)p; }

DEV bf16x8 cvt8(const float* __restrict__ p){
  const float4* q = (const float4*)p;
  float4 v0 = q[0], v1 = q[1];
  bf16x8 r;
  r[0]=(short)bf16r(v0.x); r[1]=(short)bf16r(v0.y); r[2]=(short)bf16r(v0.z); r[3]=(short)bf16r(v0.w);
  r[4]=(short)bf16r(v1.x); r[5]=(short)bf16r(v1.y); r[6]=(short)bf16r(v1.z); r[7]=(short)bf16r(v1.w);
  return r;
}

// ---------------- prep: pack weights bf16; Wc -> per-wave reg-frag layout ----
__global__ void k_prep(const float* __restrict__ d1w, const float* __restrict__ d2w,
                       const float* __restrict__ mWih, const float* __restrict__ mWhh,
                       const float* __restrict__ mbih, const float* __restrict__ mbhh,
                       const float* __restrict__ cWih, const float* __restrict__ cWhh,
                       const float* __restrict__ cbih, const float* __restrict__ cbhh,
                       unsigned short* d1w_bf, unsigned short* d2w_bf,
                       unsigned short* Wm, unsigned short* Wc, float* bm, float* bc)
{
  const long long TOT = 16384 + 49152 + 655360 + 655360 + 2560 + 2560;
  for (long long i = (long long)blockIdx.x * 256 + threadIdx.x; i < TOT;
       i += (long long)gridDim.x * 256) {
    long long x = i;
    if (x < 16384) { d1w_bf[x] = bf16r(d1w[x]); continue; }
    x -= 16384;
    if (x < 49152) { d2w_bf[x] = bf16r(d2w[x]); continue; }
    x -= 49152;
    if (x < 655360) {
      int k = (int)(x & 255); long long gg = x >> 8; // n*512+g  (k_mem layout)
      Wm[x] = bf16r(k < 128 ? mWih[gg * 128 + k] : mWhh[gg * 128 + (k - 128)]);
      continue;
    }
    x -= 655360;
    if (x < 655360) {
      int e    = (int)(x & 7);
      int lane = (int)((x >> 3) & 63);
      int kt   = (int)((x >> 9) & 7);
      int q    = (int)((x >> 12) & 3);
      int w    = (int)((x >> 14) & 7);
      int l0   = (int)(x >> 17);
      int g = q * 128 + w * 16 + (lane & 15);
      int k = kt * 32 + (lane >> 4) * 8 + e;
      Wc[x] = bf16r(k < 128 ? cWih[((size_t)l0 * 512 + g) * 128 + k]
                            : cWhh[((size_t)l0 * 512 + g) * 128 + (k - 128)]);
      continue;
    }
    x -= 655360;
    if (x < 2560) { bm[x] = mbih[x] + mbhh[x]; continue; }
    x -= 2560;
    bc[x] = cbih[x] + cbhh[x];
  }
}

// ---------------- obs = input @ d1_w^T + d1_b -> bf16 (n,b,128), staged ------
__global__ __launch_bounds__(256) void k_obs(const float* __restrict__ input,
                                             const unsigned short* __restrict__ d1w,
                                             const float* __restrict__ d1b,
                                             unsigned short* __restrict__ obs_bf)
{
  __shared__ __align__(16) unsigned short ob[64][128];

  const int m0 = blockIdx.x * 64;
  const int w = threadIdx.x >> 6, l = threadIdx.x & 63;
  const int c0l = l & 15, hi = l >> 4;

  const int arow_m = m0 + w * 16 + c0l;           // m = n*B + b
  const int n = arow_m >> 14, b = arow_m & 16383;
  const float* arow = input + ((size_t)b * NAg + n) * DD;

  f32x4 acc[8];
  #pragma unroll
  for (int nt = 0; nt < 8; nt++) acc[nt] = (f32x4){0, 0, 0, 0};

  #pragma unroll
  for (int kt = 0; kt < 4; ++kt) {
    const int k = kt * 32 + hi * 8;
    bf16x8 a = cvt8(arow + k);
    #pragma unroll
    for (int nt = 0; nt < 8; nt++) {
      bf16x8 bfr = ld8(d1w + (size_t)(nt * 16 + c0l) * DD + k);
      acc[nt] = __builtin_amdgcn_mfma_f32_16x16x32_bf16(a, bfr, acc[nt], 0, 0, 0);
    }
  }
  #pragma unroll
  for (int nt = 0; nt < 8; nt++) {
    const int col = nt * 16 + c0l;
    const float bias = d1b[col];
    #pragma unroll
    for (int j = 0; j < 4; j++) {
      const int lr = w * 16 + hi * 4 + j;
      ob[lr][col ^ ((lr & 7) << 3)] = bf16r(acc[nt][j] + bias);
    }
  }
  __syncthreads();
  #pragma unroll
  for (int cc = 0; cc < 4; ++cc) {
    const int idx = cc * 256 + threadIdx.x;
    const int r = idx >> 4;
    const int c8 = (idx & 15) << 3;
    bf16x8 v = *(const bf16x8*)&ob[r][c8 ^ ((r & 7) << 3)];
    *(bf16x8*)(obs_bf + (size_t)(m0 + r) * DD + c8) = v;
  }
}

// ---------------- mem LSTM (one step), BM=64; cat slice staged in LDS --------
__global__ __launch_bounds__(256, 2) void k_mem(const unsigned short* __restrict__ obs_bf,
                                                const float* __restrict__ h0,
                                                const float* __restrict__ c0,
                                                const unsigned short* __restrict__ Wm,
                                                const float* __restrict__ bm,
                                                float* __restrict__ out_h,
                                                float* __restrict__ out_c,
                                                unsigned short* __restrict__ cat)
{
  __shared__ __align__(16) unsigned short hm[64][128];

  const int n = blockIdx.x >> 8;
  const int b0 = (blockIdx.x & 255) << 6;
  const int w = threadIdx.x >> 6, l = threadIdx.x & 63;
  const int c0l = l & 15, hi = l >> 4;

  const unsigned short* Wn = Wm + (size_t)n * G4 * KC;
  f32x4 acc[4][8];
  #pragma unroll
  for (int mt = 0; mt < 4; mt++)
    #pragma unroll
    for (int nt = 0; nt < 8; nt++) acc[mt][nt] = (f32x4){0, 0, 0, 0};

  #pragma unroll
  for (int kt = 0; kt < 8; ++kt) {
    const int k = kt * 32 + hi * 8;
    bf16x8 bfr[8];
    #pragma unroll
    for (int nt = 0; nt < 8; nt++) {
      const int g = (nt >> 1) * 128 + w * 32 + (nt & 1) * 16 + c0l;
      bfr[nt] = ld8(Wn + (size_t)g * KC + k);
    }
    bf16x8 a[4];
    #pragma unroll
    for (int mt = 0; mt < 4; mt++) {
      const int br = b0 + mt * 16 + c0l;
      if (kt < 4) a[mt] = ld8(obs_bf + ((size_t)n * BB + br) * DD + k);
      else        a[mt] = cvt8(h0 + ((size_t)n * BB + br) * HH + (k - 128));
    }
    #pragma unroll
    for (int mt = 0; mt < 4; mt++)
      #pragma unroll
      for (int nt = 0; nt < 8; nt++)
        acc[mt][nt] = __builtin_amdgcn_mfma_f32_16x16x32_bf16(a[mt], bfr[nt], acc[mt][nt], 0, 0, 0);
  }

  #pragma unroll
  for (int uhi = 0; uhi < 2; ++uhi) {
    const int u = w * 32 + uhi * 16 + c0l;
    const float bI = bm[n * G4 + u];
    const float bF = bm[n * G4 + 128 + u];
    const float bG = bm[n * G4 + 256 + u];
    const float bO = bm[n * G4 + 384 + u];
    #pragma unroll
    for (int mt = 0; mt < 4; mt++) {
      #pragma unroll
      for (int j = 0; j < 4; j++) {
        const int r = mt * 16 + hi * 4 + j;
        const size_t rb = (size_t)n * BB + b0 + r;
        const float iv = acc[mt][0 + uhi][j] + bI;
        const float fv = acc[mt][2 + uhi][j] + bF;
        const float gv = acc[mt][4 + uhi][j] + bG;
        const float ov = acc[mt][6 + uhi][j] + bO;
        const float cold = c0[rb * HH + u];
        const float cn = sigf(fv) * cold + sigf(iv) * tanhf_(gv);
        const float hn = sigf(ov) * tanhf_(cn);
        out_h[rb * HH + u] = hn;
        out_c[rb * HH + u] = cn;
        hm[r][u ^ ((r & 7) << 3)] = bf16r(hn);
      }
    }
  }
  __syncthreads();
  #pragma unroll
  for (int cc = 0; cc < 4; ++cc) {
    const int idx = cc * 256 + threadIdx.x;
    const int r = idx >> 4;
    const int c8 = (idx & 15) << 3;
    bf16x8 v = *(const bf16x8*)&hm[r][c8 ^ ((r & 7) << 3)];
    *(bf16x8*)(cat + ((size_t)n * BB + b0 + r) * CATW + 640 + c8) = v;
  }
}

// ---------------- fused com scan: W entirely in registers --------------------
// 512 thr / 8 waves; wave w owns hidden units [w*16, w*16+16), all 4 gates,
// full K=256: 32 B-frags = 128 VGPRs, loaded once. waves_per_eu pinned to 2
// so the allocator keeps them resident (round-9: VGPR=120 -> W was re-fetched).
__global__ __launch_bounds__(512)
__attribute__((amdgpu_waves_per_eu(2, 2)))
void k_comf(const unsigned short* __restrict__ obs_bf,
            const unsigned short* __restrict__ Wpk,
            const float* __restrict__ bc,
            unsigned short* __restrict__ cat)
{
  __shared__ __align__(16) unsigned short hl[2][64][128];   // 32 KB

  const int bid = blockIdx.x;
  const int swz = (bid & 7) * 160 + (bid >> 3);   // 1280 = 8*160, bijective
  const int l0 = swz >> 8;
  const int b0 = (swz & 255) << 6;
  const int tid = threadIdx.x;
  const int w = tid >> 6, lane = tid & 63;
  const int c0l = lane & 15, hi = lane >> 4;
  const int u = w * 16 + c0l;

  // ---- load all W fragments into registers (one contiguous 1KB line/frag) --
  const unsigned short* Wg = Wpk + (size_t)l0 * 131072 + (size_t)w * 16384 + lane * 8;
  bf16x8 wfr[4][8];
  #pragma unroll
  for (int q = 0; q < 4; q++)
    #pragma unroll
    for (int kt = 0; kt < 8; kt++)
      wfr[q][kt] = ld8(Wg + (q * 8 + kt) * 512);

  const float bI = bc[l0 * G4 + u];
  const float bF = bc[l0 * G4 + 128 + u];
  const float bG = bc[l0 * G4 + 256 + u];
  const float bO = bc[l0 * G4 + 384 + u];

  // zero h(-1) buffer (hl[1], read by t=0)
  for (int i = tid; i < 8192; i += 512) ((unsigned short*)hl)[8192 + i] = 0;
  __syncthreads();

  float creg[2][2][4];
  #pragma unroll
  for (int hh = 0; hh < 2; hh++)
    #pragma unroll
    for (int m2 = 0; m2 < 2; m2++)
      #pragma unroll
      for (int j = 0; j < 4; j++) creg[hh][m2][j] = 0.0f;

  for (int t = 0; t < 5; ++t) {
    const int it = (t == 4) ? l0 : (t + (t >= l0 ? 1 : 0));
    const unsigned short* obsb = obs_bf + ((size_t)it * BB + b0) * DD;
    const int rbuf = (t + 1) & 1, wbuf = t & 1;

    #pragma unroll
    for (int hh = 0; hh < 2; hh++) {
      f32x4 acc[2][4];
      #pragma unroll
      for (int m2 = 0; m2 < 2; m2++)
        #pragma unroll
        for (int q = 0; q < 4; q++) acc[m2][q] = (f32x4){0, 0, 0, 0};

      #pragma unroll
      for (int kt = 0; kt < 8; ++kt) {
        bf16x8 a[2];
        #pragma unroll
        for (int m2 = 0; m2 < 2; m2++) {
          const int r = (hh * 2 + m2) * 16 + c0l;
          if (kt < 4) a[m2] = ld8(obsb + (size_t)r * DD + kt * 32 + hi * 8);
          else        a[m2] = ld8(&hl[rbuf][r][((kt - 4) * 32 + hi * 8) ^ ((r & 7) << 3)]);
        }
        #pragma unroll
        for (int m2 = 0; m2 < 2; m2++)
          #pragma unroll
          for (int q = 0; q < 4; q++)
            acc[m2][q] = __builtin_amdgcn_mfma_f32_16x16x32_bf16(a[m2], wfr[q][kt], acc[m2][q], 0, 0, 0);
      }

      // epilogue for this 32-row half
      #pragma unroll
      for (int m2 = 0; m2 < 2; m2++) {
        #pragma unroll
        for (int j = 0; j < 4; j++) {
          const int r = hh * 32 + m2 * 16 + hi * 4 + j;
          const float iv = acc[m2][0][j] + bI;
          const float fv = acc[m2][1][j] + bF;
          const float gv = acc[m2][2][j] + bG;
          const float ov = acc[m2][3][j] + bO;
          const float cn = sigf(fv) * creg[hh][m2][j] + sigf(iv) * tanhf_(gv);
          const float hn = sigf(ov) * tanhf_(cn);
          creg[hh][m2][j] = cn;
          hl[wbuf][r][u ^ ((r & 7) << 3)] = bf16r(hn);
        }
      }
    }
    __syncthreads();

    // coalesced wide copy hl[wbuf] -> cat (full 128B lines)
    unsigned short* catb = cat + ((size_t)it * BB + b0) * CATW + l0 * 128;
    #pragma unroll
    for (int cc = 0; cc < 2; ++cc) {
      const int idx = cc * 512 + tid;          // 0..1023
      const int r = idx >> 4;
      const int c8 = (idx & 15) << 3;
      bf16x8 v = *(const bf16x8*)&hl[wbuf][r][c8 ^ ((r & 7) << 3)];
      *(bf16x8*)(catb + (size_t)r * CATW + c8) = v;
    }
  }
}

// ---------------- outs = cat @ d2_w^T + d2_b  -> d_out[0 .. 5*B*64) ----------
__global__ __launch_bounds__(256) void k_d2(const unsigned short* __restrict__ cat,
                                            const unsigned short* __restrict__ d2w,
                                            const float* __restrict__ d2b,
                                            float* __restrict__ out)
{
  const int m0 = blockIdx.x * 64;
  const int w = threadIdx.x >> 6, l = threadIdx.x & 63;
  const int c0l = l & 15, hi = l >> 4;

  const unsigned short* arow = cat + (size_t)(m0 + w * 16 + c0l) * CATW;
  f32x4 acc[4];
  #pragma unroll
  for (int nt = 0; nt < 4; nt++) acc[nt] = (f32x4){0, 0, 0, 0};

  #pragma unroll 4
  for (int kt = 0; kt < 24; ++kt) {
    const int k = kt * 32 + hi * 8;
    bf16x8 a = ld8(arow + k);
    #pragma unroll
    for (int nt = 0; nt < 4; nt++) {
      bf16x8 bfr = ld8(d2w + (size_t)(nt * 16 + c0l) * CATW + k);
      acc[nt] = __builtin_amdgcn_mfma_f32_16x16x32_bf16(a, bfr, acc[nt], 0, 0, 0);
    }
  }
  #pragma unroll
  for (int nt = 0; nt < 4; nt++) {
    const int col = nt * 16 + c0l;
    const float bias = d2b[col];
    #pragma unroll
    for (int j = 0; j < 4; j++) {
      const int r = m0 + w * 16 + hi * 4 + j;
      out[(size_t)r * AA + col] = acc[nt][j] + bias;
    }
  }
}

extern "C" void kernel_launch(void* const* d_in, const int* in_sizes, int n_in,
                              void* d_out, int out_size, void* d_ws, size_t ws_size,
                              hipStream_t stream)
{
  const float* input = (const float*)d_in[0];
  const float* h0    = (const float*)d_in[1];
  const float* c0    = (const float*)d_in[2];
  const float* d1w   = (const float*)d_in[3];
  const float* d1b   = (const float*)d_in[4];
  const float* d2w   = (const float*)d_in[5];
  const float* d2b   = (const float*)d_in[6];
  const float* mWih  = (const float*)d_in[7];
  const float* mWhh  = (const float*)d_in[8];
  const float* mbih  = (const float*)d_in[9];
  const float* mbhh  = (const float*)d_in[10];
  const float* cWih  = (const float*)d_in[11];
  const float* cWhh  = (const float*)d_in[12];
  const float* cbih  = (const float*)d_in[13];
  const float* cbhh  = (const float*)d_in[14];
  float* out = (float*)d_out;

  char* ws = (char*)d_ws;
  size_t off = 0;
  auto alloc = [&](size_t bytes) { void* p = ws + off; off += (bytes + 255) & ~255ull; return p; };
  unsigned short* d1w_bf = (unsigned short*)alloc(16384 * 2);
  unsigned short* d2w_bf = (unsigned short*)alloc(49152 * 2);
  unsigned short* Wm     = (unsigned short*)alloc(655360 * 2);
  unsigned short* Wcb    = (unsigned short*)alloc(655360 * 2);
  float* bm              = (float*)alloc(2560 * 4);
  float* bc              = (float*)alloc(2560 * 4);
  unsigned short* obs_bf = (unsigned short*)alloc((size_t)NAg * BB * DD * 2);
  unsigned short* cat    = (unsigned short*)alloc((size_t)NAg * BB * CATW * 2);

  float* out_h = out + (size_t)NAg * BB * AA;
  float* out_c = out_h + (size_t)NAg * BB * HH;

  k_prep<<<2048, 256, 0, stream>>>(d1w, d2w, mWih, mWhh, mbih, mbhh,
                                   cWih, cWhh, cbih, cbhh,
                                   d1w_bf, d2w_bf, Wm, Wcb, bm, bc);
  k_obs<<<(NAg * BB) / 64, 256, 0, stream>>>(input, d1w_bf, d1b, obs_bf);
  k_mem<<<(NAg * BB) / 64, 256, 0, stream>>>(obs_bf, h0, c0, Wm, bm, out_h, out_c, cat);
  k_comf<<<(NAg * BB) / 64, 512, 0, stream>>>(obs_bf, Wcb, bc, cat);
  k_d2<<<(NAg * BB) / 64, 256, 0, stream>>>(cat, d2w_bf, d2b, out);
}

// Round 11
// 388.018 us; speedup vs baseline: 2.3064x; 1.1020x over previous
//
#include <hip/hip_runtime.h>

#define BB   16384
#define NAg  5
#define DD   128
#define HH   128
#define G4   512   // 4*H
#define KC   256   // LS1 + H
#define AA   64
#define CATW 768   // 6*H

typedef __attribute__((ext_vector_type(8))) short bf16x8;
typedef __attribute__((ext_vector_type(4))) float f32x4;

#define DEV static __device__ __forceinline__

DEV unsigned short bf16r(float x){
  unsigned u = __float_as_uint(x);
  unsigned r = (u + 0x7fffu + ((u >> 16) & 1u)) >> 16;
  return (unsigned short)r;
}
// fast sigmoid/tanh: v_rcp_f32 (1 ULP) instead of IEEE division
DEV float sigf(float x){ return __builtin_amdgcn_rcpf(1.0f + __expf(-x)); }
DEV float tanhf_(float x){ return __builtin_fmaf(2.0f, __builtin_amdgcn_rcpf(1.0f + __expf(-2.0f * x)), -1.0f); }

DEV bf16x8 ld8(const unsigned short* p){ return *(const bf16x8*)p; }

DEV bf16x8 cvt8(const float* __restrict__ p){
  const float4* q = (const float4*)p;
  float4 v0 = q[0], v1 = q[1];
  bf16x8 r;
  r[0]=(short)bf16r(v0.x); r[1]=(short)bf16r(v0.y); r[2]=(short)bf16r(v0.z); r[3]=(short)bf16r(v0.w);
  r[4]=(short)bf16r(v1.x); r[5]=(short)bf16r(v1.y); r[6]=(short)bf16r(v1.z); r[7]=(short)bf16r(v1.w);
  return r;
}

// ---------------- prep: pack weights bf16; Wm/Wc -> per-wave reg-frag layout -
// [n][w][q][kt][lane][8]: lane holds W[g=q*128+w*16+(lane&15)][k=kt*32+(lane>>4)*8+e]
__global__ void k_prep(const float* __restrict__ d1w, const float* __restrict__ d2w,
                       const float* __restrict__ mWih, const float* __restrict__ mWhh,
                       const float* __restrict__ mbih, const float* __restrict__ mbhh,
                       const float* __restrict__ cWih, const float* __restrict__ cWhh,
                       const float* __restrict__ cbih, const float* __restrict__ cbhh,
                       unsigned short* d1w_bf, unsigned short* d2w_bf,
                       unsigned short* Wm, unsigned short* Wc, float* bm, float* bc)
{
  const long long TOT = 16384 + 49152 + 655360 + 655360 + 2560 + 2560;
  for (long long i = (long long)blockIdx.x * 256 + threadIdx.x; i < TOT;
       i += (long long)gridDim.x * 256) {
    long long x = i;
    if (x < 16384) { d1w_bf[x] = bf16r(d1w[x]); continue; }
    x -= 16384;
    if (x < 49152) { d2w_bf[x] = bf16r(d2w[x]); continue; }
    x -= 49152;
    if (x < 655360) {
      int e    = (int)(x & 7);
      int lane = (int)((x >> 3) & 63);
      int kt   = (int)((x >> 9) & 7);
      int q    = (int)((x >> 12) & 3);
      int w    = (int)((x >> 14) & 7);
      int n    = (int)(x >> 17);
      int g = q * 128 + w * 16 + (lane & 15);
      int k = kt * 32 + (lane >> 4) * 8 + e;
      Wm[x] = bf16r(k < 128 ? mWih[((size_t)n * 512 + g) * 128 + k]
                            : mWhh[((size_t)n * 512 + g) * 128 + (k - 128)]);
      continue;
    }
    x -= 655360;
    if (x < 655360) {
      int e    = (int)(x & 7);
      int lane = (int)((x >> 3) & 63);
      int kt   = (int)((x >> 9) & 7);
      int q    = (int)((x >> 12) & 3);
      int w    = (int)((x >> 14) & 7);
      int l0   = (int)(x >> 17);
      int g = q * 128 + w * 16 + (lane & 15);
      int k = kt * 32 + (lane >> 4) * 8 + e;
      Wc[x] = bf16r(k < 128 ? cWih[((size_t)l0 * 512 + g) * 128 + k]
                            : cWhh[((size_t)l0 * 512 + g) * 128 + (k - 128)]);
      continue;
    }
    x -= 655360;
    if (x < 2560) { bm[x] = mbih[x] + mbhh[x]; continue; }
    x -= 2560;
    bc[x] = cbih[x] + cbhh[x];
  }
}

// ---------------- obs = input @ d1_w^T + d1_b -> bf16 (n,b,128), staged ------
__global__ __launch_bounds__(256) void k_obs(const float* __restrict__ input,
                                             const unsigned short* __restrict__ d1w,
                                             const float* __restrict__ d1b,
                                             unsigned short* __restrict__ obs_bf)
{
  __shared__ __align__(16) unsigned short ob[64][128];

  const int m0 = blockIdx.x * 64;
  const int w = threadIdx.x >> 6, l = threadIdx.x & 63;
  const int c0l = l & 15, hi = l >> 4;

  const int arow_m = m0 + w * 16 + c0l;           // m = n*B + b
  const int n = arow_m >> 14, b = arow_m & 16383;
  const float* arow = input + ((size_t)b * NAg + n) * DD;

  f32x4 acc[8];
  #pragma unroll
  for (int nt = 0; nt < 8; nt++) acc[nt] = (f32x4){0, 0, 0, 0};

  #pragma unroll
  for (int kt = 0; kt < 4; ++kt) {
    const int k = kt * 32 + hi * 8;
    bf16x8 a = cvt8(arow + k);
    #pragma unroll
    for (int nt = 0; nt < 8; nt++) {
      bf16x8 bfr = ld8(d1w + (size_t)(nt * 16 + c0l) * DD + k);
      acc[nt] = __builtin_amdgcn_mfma_f32_16x16x32_bf16(a, bfr, acc[nt], 0, 0, 0);
    }
  }
  #pragma unroll
  for (int nt = 0; nt < 8; nt++) {
    const int col = nt * 16 + c0l;
    const float bias = d1b[col];
    #pragma unroll
    for (int j = 0; j < 4; j++) {
      const int lr = w * 16 + hi * 4 + j;
      ob[lr][col ^ ((lr & 7) << 3)] = bf16r(acc[nt][j] + bias);
    }
  }
  __syncthreads();
  #pragma unroll
  for (int cc = 0; cc < 4; ++cc) {
    const int idx = cc * 256 + threadIdx.x;
    const int r = idx >> 4;
    const int c8 = (idx & 15) << 3;
    bf16x8 v = *(const bf16x8*)&ob[r][c8 ^ ((r & 7) << 3)];
    *(bf16x8*)(obs_bf + (size_t)(m0 + r) * DD + c8) = v;
  }
}

// ---------------- mem LSTM, reg-W style: 512 thr, W resident -----------------
__global__ __launch_bounds__(512) void k_mem(const unsigned short* __restrict__ obs_bf,
                                             const float* __restrict__ h0,
                                             const float* __restrict__ c0,
                                             const unsigned short* __restrict__ Wmp,
                                             const float* __restrict__ bm,
                                             float* __restrict__ out_h,
                                             float* __restrict__ out_c,
                                             unsigned short* __restrict__ cat)
{
  __shared__ __align__(16) float hs[64][128];   // 32 KB f32 staging

  const int n = blockIdx.x >> 8;
  const int b0 = (blockIdx.x & 255) << 6;
  const int tid = threadIdx.x;
  const int w = tid >> 6, lane = tid & 63;
  const int c0l = lane & 15, hi = lane >> 4;
  const int u = w * 16 + c0l;

  const unsigned short* Wg = Wmp + (size_t)n * 131072 + (size_t)w * 16384 + lane * 8;
  bf16x8 wfr[4][8];
  #pragma unroll
  for (int q = 0; q < 4; q++)
    #pragma unroll
    for (int kt = 0; kt < 8; kt++)
      wfr[q][kt] = ld8(Wg + (q * 8 + kt) * 512);

  const float bI = bm[n * G4 + u];
  const float bF = bm[n * G4 + 128 + u];
  const float bG = bm[n * G4 + 256 + u];
  const float bO = bm[n * G4 + 384 + u];

  float cnr[2][2][4];

  #pragma unroll
  for (int hh = 0; hh < 2; hh++) {
    f32x4 acc[2][4];
    #pragma unroll
    for (int m2 = 0; m2 < 2; m2++)
      #pragma unroll
      for (int q = 0; q < 4; q++) acc[m2][q] = (f32x4){0, 0, 0, 0};

    #pragma unroll
    for (int kt = 0; kt < 8; ++kt) {
      bf16x8 a[2];
      #pragma unroll
      for (int m2 = 0; m2 < 2; m2++) {
        const int r = (hh * 2 + m2) * 16 + c0l;
        if (kt < 4) a[m2] = ld8(obs_bf + ((size_t)n * BB + b0 + r) * DD + kt * 32 + hi * 8);
        else        a[m2] = cvt8(h0 + ((size_t)n * BB + b0 + r) * HH + (kt - 4) * 32 + hi * 8);
      }
      #pragma unroll
      for (int m2 = 0; m2 < 2; m2++)
        #pragma unroll
        for (int q = 0; q < 4; q++)
          acc[m2][q] = __builtin_amdgcn_mfma_f32_16x16x32_bf16(a[m2], wfr[q][kt], acc[m2][q], 0, 0, 0);
    }

    #pragma unroll
    for (int m2 = 0; m2 < 2; m2++) {
      #pragma unroll
      for (int j = 0; j < 4; j++) {
        const int r = hh * 32 + m2 * 16 + hi * 4 + j;
        const float iv = acc[m2][0][j] + bI;
        const float fv = acc[m2][1][j] + bF;
        const float gv = acc[m2][2][j] + bG;
        const float ov = acc[m2][3][j] + bO;
        const float cold = c0[((size_t)n * BB + b0 + r) * HH + u];
        const float cn = sigf(fv) * cold + sigf(iv) * tanhf_(gv);
        const float hn = sigf(ov) * tanhf_(cn);
        cnr[hh][m2][j] = cn;
        hs[r][u ^ ((r & 7) << 3)] = hn;
      }
    }
  }
  __syncthreads();
  // out_h copy (float4, full lines)
  #pragma unroll
  for (int cc = 0; cc < 4; ++cc) {
    const int idx = cc * 512 + tid;
    const int r = idx >> 5;
    const int c4 = (idx & 31) << 2;
    float4 v = *(const float4*)&hs[r][c4 ^ ((r & 7) << 3)];
    *(float4*)(out_h + ((size_t)n * BB + b0 + r) * HH + c4) = v;
  }
  // cat copy (bf16x8, full lines)
  #pragma unroll
  for (int cc = 0; cc < 2; ++cc) {
    const int idx = cc * 512 + tid;
    const int r = idx >> 4;
    const int c8 = (idx & 15) << 3;
    const float* p = &hs[r][c8 ^ ((r & 7) << 3)];
    float4 v0 = *(const float4*)p, v1 = *(const float4*)(p + 4);
    bf16x8 bv;
    bv[0]=(short)bf16r(v0.x); bv[1]=(short)bf16r(v0.y); bv[2]=(short)bf16r(v0.z); bv[3]=(short)bf16r(v0.w);
    bv[4]=(short)bf16r(v1.x); bv[5]=(short)bf16r(v1.y); bv[6]=(short)bf16r(v1.z); bv[7]=(short)bf16r(v1.w);
    *(bf16x8*)(cat + ((size_t)n * BB + b0 + r) * CATW + 640 + c8) = bv;
  }
  __syncthreads();
  // stage c and copy
  #pragma unroll
  for (int hh = 0; hh < 2; hh++)
    #pragma unroll
    for (int m2 = 0; m2 < 2; m2++)
      #pragma unroll
      for (int j = 0; j < 4; j++) {
        const int r = hh * 32 + m2 * 16 + hi * 4 + j;
        hs[r][u ^ ((r & 7) << 3)] = cnr[hh][m2][j];
      }
  __syncthreads();
  #pragma unroll
  for (int cc = 0; cc < 4; ++cc) {
    const int idx = cc * 512 + tid;
    const int r = idx >> 5;
    const int c4 = (idx & 31) << 2;
    float4 v = *(const float4*)&hs[r][c4 ^ ((r & 7) << 3)];
    *(float4*)(out_c + ((size_t)n * BB + b0 + r) * HH + c4) = v;
  }
}

// ---------------- fused com scan: reg-W + phase-skewed schedule --------------
// Per step: [hh0: obs-MFMA, BARRIER, h-MFMA, epi] [hh1: obs-MFMA, h-MFMA, epi]
// BARRIER, cat-copy. obs-MFMAs (no LDS dep) overlap prior epilogue VALU.
__global__ __launch_bounds__(512) void k_comf(const unsigned short* __restrict__ obs_bf,
                                              const unsigned short* __restrict__ Wpk,
                                              const float* __restrict__ bc,
                                              unsigned short* __restrict__ cat)
{
  __shared__ __align__(16) unsigned short hl[2][64][128];   // 32 KB

  const int bid = blockIdx.x;
  const int swz = (bid & 7) * 160 + (bid >> 3);   // 1280 = 8*160, bijective
  const int l0 = swz >> 8;
  const int b0 = (swz & 255) << 6;
  const int tid = threadIdx.x;
  const int w = tid >> 6, lane = tid & 63;
  const int c0l = lane & 15, hi = lane >> 4;
  const int u = w * 16 + c0l;

  const unsigned short* Wg = Wpk + (size_t)l0 * 131072 + (size_t)w * 16384 + lane * 8;
  bf16x8 wfr[4][8];
  #pragma unroll
  for (int q = 0; q < 4; q++)
    #pragma unroll
    for (int kt = 0; kt < 8; kt++)
      wfr[q][kt] = ld8(Wg + (q * 8 + kt) * 512);

  const float bI = bc[l0 * G4 + u];
  const float bF = bc[l0 * G4 + 128 + u];
  const float bG = bc[l0 * G4 + 256 + u];
  const float bO = bc[l0 * G4 + 384 + u];

  // zero h(-1) buffer (hl[1], read by t=0)
  for (int i = tid; i < 8192; i += 512) ((unsigned short*)hl)[8192 + i] = 0;
  __syncthreads();

  float creg[2][2][4];
  #pragma unroll
  for (int hh = 0; hh < 2; hh++)
    #pragma unroll
    for (int m2 = 0; m2 < 2; m2++)
      #pragma unroll
      for (int j = 0; j < 4; j++) creg[hh][m2][j] = 0.0f;

  for (int t = 0; t < 5; ++t) {
    const int it = (t == 4) ? l0 : (t + (t >= l0 ? 1 : 0));
    const unsigned short* obsb = obs_bf + ((size_t)it * BB + b0) * DD;
    const int rbuf = (t + 1) & 1, wbuf = t & 1;

    #pragma unroll
    for (int hh = 0; hh < 2; hh++) {
      f32x4 acc[2][4];
      #pragma unroll
      for (int m2 = 0; m2 < 2; m2++)
        #pragma unroll
        for (int q = 0; q < 4; q++) acc[m2][q] = (f32x4){0, 0, 0, 0};

      // obs-part (kt 0..3) — no LDS dependency; overlaps prior epilogue
      #pragma unroll
      for (int kt = 0; kt < 4; ++kt) {
        bf16x8 a[2];
        #pragma unroll
        for (int m2 = 0; m2 < 2; m2++) {
          const int r = (hh * 2 + m2) * 16 + c0l;
          a[m2] = ld8(obsb + (size_t)r * DD + kt * 32 + hi * 8);
        }
        #pragma unroll
        for (int m2 = 0; m2 < 2; m2++)
          #pragma unroll
          for (int q = 0; q < 4; q++)
            acc[m2][q] = __builtin_amdgcn_mfma_f32_16x16x32_bf16(a[m2], wfr[q][kt], acc[m2][q], 0, 0, 0);
      }

      if (hh == 0) __syncthreads();   // hl[rbuf] from step t-1 now certified

      // h-part (kt 4..7) from LDS
      #pragma unroll
      for (int kt = 4; kt < 8; ++kt) {
        bf16x8 a[2];
        #pragma unroll
        for (int m2 = 0; m2 < 2; m2++) {
          const int r = (hh * 2 + m2) * 16 + c0l;
          a[m2] = ld8(&hl[rbuf][r][((kt - 4) * 32 + hi * 8) ^ ((r & 7) << 3)]);
        }
        #pragma unroll
        for (int m2 = 0; m2 < 2; m2++)
          #pragma unroll
          for (int q = 0; q < 4; q++)
            acc[m2][q] = __builtin_amdgcn_mfma_f32_16x16x32_bf16(a[m2], wfr[q][kt], acc[m2][q], 0, 0, 0);
      }

      // epilogue
      #pragma unroll
      for (int m2 = 0; m2 < 2; m2++) {
        #pragma unroll
        for (int j = 0; j < 4; j++) {
          const int r = hh * 32 + m2 * 16 + hi * 4 + j;
          const float iv = acc[m2][0][j] + bI;
          const float fv = acc[m2][1][j] + bF;
          const float gv = acc[m2][2][j] + bG;
          const float ov = acc[m2][3][j] + bO;
          const float cn = sigf(fv) * creg[hh][m2][j] + sigf(iv) * tanhf_(gv);
          const float hn = sigf(ov) * tanhf_(cn);
          creg[hh][m2][j] = cn;
          hl[wbuf][r][u ^ ((r & 7) << 3)] = bf16r(hn);
        }
      }
    }
    __syncthreads();

    // coalesced wide copy hl[wbuf] -> cat
    unsigned short* catb = cat + ((size_t)it * BB + b0) * CATW + l0 * 128;
    #pragma unroll
    for (int cc = 0; cc < 2; ++cc) {
      const int idx = cc * 512 + tid;
      const int r = idx >> 4;
      const int c8 = (idx & 15) << 3;
      bf16x8 v = *(const bf16x8*)&hl[wbuf][r][c8 ^ ((r & 7) << 3)];
      *(bf16x8*)(catb + (size_t)r * CATW + c8) = v;
    }
  }
}

// ---------------- outs = cat @ d2_w^T + d2_b, 128 rows/block -----------------
__global__ __launch_bounds__(256) void k_d2(const unsigned short* __restrict__ cat,
                                            const unsigned short* __restrict__ d2w,
                                            const float* __restrict__ d2b,
                                            float* __restrict__ out)
{
  const int m0 = blockIdx.x * 128;
  const int w = threadIdx.x >> 6, l = threadIdx.x & 63;
  const int c0l = l & 15, hi = l >> 4;

  const unsigned short* arow0 = cat + (size_t)(m0 + w * 16 + c0l) * CATW;
  const unsigned short* arow1 = arow0 + (size_t)64 * CATW;
  f32x4 acc[2][4];
  #pragma unroll
  for (int mt = 0; mt < 2; mt++)
    #pragma unroll
    for (int nt = 0; nt < 4; nt++) acc[mt][nt] = (f32x4){0, 0, 0, 0};

  #pragma unroll 4
  for (int kt = 0; kt < 24; ++kt) {
    const int k = kt * 32 + hi * 8;
    bf16x8 a0 = ld8(arow0 + k);
    bf16x8 a1 = ld8(arow1 + k);
    #pragma unroll
    for (int nt = 0; nt < 4; nt++) {
      bf16x8 bfr = ld8(d2w + (size_t)(nt * 16 + c0l) * CATW + k);
      acc[0][nt] = __builtin_amdgcn_mfma_f32_16x16x32_bf16(a0, bfr, acc[0][nt], 0, 0, 0);
      acc[1][nt] = __builtin_amdgcn_mfma_f32_16x16x32_bf16(a1, bfr, acc[1][nt], 0, 0, 0);
    }
  }
  #pragma unroll
  for (int mt = 0; mt < 2; mt++) {
    #pragma unroll
    for (int nt = 0; nt < 4; nt++) {
      const int col = nt * 16 + c0l;
      const float bias = d2b[col];
      #pragma unroll
      for (int j = 0; j < 4; j++) {
        const int r = m0 + mt * 64 + w * 16 + hi * 4 + j;
        out[(size_t)r * AA + col] = acc[mt][nt][j] + bias;
      }
    }
  }
}

extern "C" void kernel_launch(void* const* d_in, const int* in_sizes, int n_in,
                              void* d_out, int out_size, void* d_ws, size_t ws_size,
                              hipStream_t stream)
{
  const float* input = (const float*)d_in[0];
  const float* h0    = (const float*)d_in[1];
  const float* c0    = (const float*)d_in[2];
  const float* d1w   = (const float*)d_in[3];
  const float* d1b   = (const float*)d_in[4];
  const float* d2w   = (const float*)d_in[5];
  const float* d2b   = (const float*)d_in[6];
  const float* mWih  = (const float*)d_in[7];
  const float* mWhh  = (const float*)d_in[8];
  const float* mbih  = (const float*)d_in[9];
  const float* mbhh  = (const float*)d_in[10];
  const float* cWih  = (const float*)d_in[11];
  const float* cWhh  = (const float*)d_in[12];
  const float* cbih  = (const float*)d_in[13];
  const float* cbhh  = (const float*)d_in[14];
  float* out = (float*)d_out;

  char* ws = (char*)d_ws;
  size_t off = 0;
  auto alloc = [&](size_t bytes) { void* p = ws + off; off += (bytes + 255) & ~255ull; return p; };
  unsigned short* d1w_bf = (unsigned short*)alloc(16384 * 2);
  unsigned short* d2w_bf = (unsigned short*)alloc(49152 * 2);
  unsigned short* Wm     = (unsigned short*)alloc(655360 * 2);
  unsigned short* Wcb    = (unsigned short*)alloc(655360 * 2);
  float* bm              = (float*)alloc(2560 * 4);
  float* bc              = (float*)alloc(2560 * 4);
  unsigned short* obs_bf = (unsigned short*)alloc((size_t)NAg * BB * DD * 2);
  unsigned short* cat    = (unsigned short*)alloc((size_t)NAg * BB * CATW * 2);

  float* out_h = out + (size_t)NAg * BB * AA;
  float* out_c = out_h + (size_t)NAg * BB * HH;

  k_prep<<<2048, 256, 0, stream>>>(d1w, d2w, mWih, mWhh, mbih, mbhh,
                                   cWih, cWhh, cbih, cbhh,
                                   d1w_bf, d2w_bf, Wm, Wcb, bm, bc);
  k_obs<<<(NAg * BB) / 64, 256, 0, stream>>>(input, d1w_bf, d1b, obs_bf);
  k_mem<<<(NAg * BB) / 64, 512, 0, stream>>>(obs_bf, h0, c0, Wm, bm, out_h, out_c, cat);
  k_comf<<<(NAg * BB) / 64, 512, 0, stream>>>(obs_bf, Wcb, bc, cat);
  k_d2<<<(NAg * BB) / 128, 256, 0, stream>>>(cat, d2w_bf, d2b, out);
}